// Round 13
// baseline (65.741 us; speedup 1.0000x reference)
//
#include <hip/hip_runtime.h>
#include <math.h>

#define N_NODES 2000
#define N_EDGES 32000
#define BB 16
#define TT 20
#define NG (BB*TT)      // 320 graphs
#define OUTF 8
#define HID 24
#define FC_OUTD 160
#define FCC_OUTD 20

// single-u64 fixed-point pack (one native ds_add_u64 per edge):
//   bits[ 0:26) t1' = sum num*(x+8)  @ 2^12   max ~17.7M  < 2^26 = 67.1M
//   bits[26:46) den = sum num        @ 2^11   max ~681K   < 2^20 = 1.05M
//   bits[46:64) t2  = sum num*w      @ 2^9    max ~170K   < 2^18 = 262K
// recover: ratio1 = 0.5*t1i/deni - 8 ; ratio2 = 4*t2i/deni

// ws layout (bytes)
#define WS_PACK   0         // u32[32000]: src | dst<<16
#define WS_FEATS  131072    // float[NG*OUTF]
#define WS_M      141312    // float[480]
#define WS_B2     143232    // float[20]

// ---------- builder: pack src|dst (+ extra block: fused fcc@fc projection) ----------

__global__ __launch_bounds__(1024) void build_pack(
    const int* __restrict__ src, const int* __restrict__ dst,
    unsigned* __restrict__ pack,
    const float* __restrict__ fc_w, const float* __restrict__ fc_b,
    const float* __restrict__ fcc_w, const float* __restrict__ fcc_b,
    float* __restrict__ Mout, float* __restrict__ b2out)
{
    const int tid = threadIdx.x;
    if (blockIdx.x == 32) {   // prep block: M = fcc_w @ fc_w ; b2 = fcc_b + fcc_w @ fc_b
        if (tid < FCC_OUTD * HID) {
            const int j = tid / HID, h = tid % HID;
            float acc = 0.f;
#pragma unroll 4
            for (int m = 0; m < FC_OUTD; ++m)
                acc += fcc_w[j * FC_OUTD + m] * fc_w[m * HID + h];
            Mout[tid] = acc;
        } else if (tid < FCC_OUTD * HID + FCC_OUTD) {
            const int j = tid - FCC_OUTD * HID;
            float acc = fcc_b[j];
#pragma unroll 4
            for (int m = 0; m < FC_OUTD; ++m)
                acc += fcc_w[j * FC_OUTD + m] * fc_b[m];
            b2out[j] = acc;
        }
        return;
    }
    const int e = blockIdx.x * 1024 + tid;
    if (e < N_EDGES)
        pack[e] = (unsigned)src[e] | ((unsigned)dst[e] << 16);
}

// ---- GAT: 1 block (512 thr)/graph; register-prefetched edges + single ds_add_u64 ----

__global__ __launch_bounds__(512) void gat_atomic(
    const float* __restrict__ x, const float* __restrict__ edge_w,
    const unsigned* __restrict__ pack,
    const float* __restrict__ W_node, const float* __restrict__ W_edge,
    const float* __restrict__ attn_l, const float* __restrict__ attn_e,
    const float* __restrict__ attn_r, const float* __restrict__ gat_b,
    float* __restrict__ feats)
{
    __shared__ float              xs[N_NODES];     // 8 KB
    __shared__ unsigned long long apk[N_NODES];    // 16 KB
    __shared__ double wr1[8], wr2[8];

    const int g   = blockIdx.x;
    const int tid = threadIdx.x;

    // rank-1 projections collapse to 3 scalars
    float cl = 0.f, ce = 0.f, cr = 0.f;
#pragma unroll
    for (int k = 0; k < OUTF; ++k) {
        cl += W_node[k] * attn_l[k];
        cr += W_node[k] * attn_r[k];
        ce += W_edge[k] * attn_e[k];
    }

    const float* xg = x + (size_t)g * N_NODES;
    const float* wg = edge_w + (size_t)g * N_EDGES;

    if (tid < N_NODES / 4)
        ((float4*)xs)[tid] = ((const float4*)xg)[tid];
    for (int i = tid; i < N_NODES; i += 512) apk[i] = 0ull;

    // ---- issue ALL edge loads into registers (A/B halves, unguarded except tail) ----
    const int4*   pk4 = (const int4*)pack;
    const float4* wg4 = (const float4*)wg;
    int4   pA[8], pB[8];
    float4 wA[8], wB[8];
#pragma unroll
    for (int k = 0; k < 8; ++k) {
        const int c = tid + k * 512;
        pA[k] = pk4[c];
        wA[k] = wg4[c];
    }
#pragma unroll
    for (int k = 0; k < 8; ++k) {
        const int c = tid + (k + 8) * 512;
        if ((k < 7) || (tid < 320)) { pB[k] = pk4[c]; wB[k] = wg4[c]; }
    }

    __syncthreads();   // xs/apk ready

#define EDGE(mv, wv)                                                      \
    {                                                                     \
        const int   s   = (int)((mv) & 0xffffu);                          \
        const int   d   = (int)((mv) >> 16);                              \
        const float w   = (wv);                                           \
        const float xsv = xs[s];                                          \
        const float xdv = xs[d];                                          \
        float ev = cl * xsv + ce * w + cr * xdv;                          \
        ev = fmaxf(ev, 0.2f * ev);                                        \
        const float num = __expf(ev);                                     \
        const float p   = num * 4096.0f;                                  \
        const unsigned t1i  = __float2uint_rn(fmaf(p, xsv, 8.0f * p));    \
        const unsigned deni = __float2uint_rn(num * 2048.0f);             \
        const unsigned t2i  = __float2uint_rn(num * w * 512.0f);          \
        const unsigned long long inc = (unsigned long long)t1i            \
              | ((unsigned long long)deni << 26)                          \
              | ((unsigned long long)t2i  << 46);                         \
        atomicAdd(&apk[d], inc);                                          \
    }

#pragma unroll
    for (int k = 0; k < 8; ++k) {
        EDGE((unsigned)pA[k].x, wA[k].x);
        EDGE((unsigned)pA[k].y, wA[k].y);
        EDGE((unsigned)pA[k].z, wA[k].z);
        EDGE((unsigned)pA[k].w, wA[k].w);
    }
#pragma unroll
    for (int k = 0; k < 8; ++k) {
        if ((k < 7) || (tid < 320)) {
            EDGE((unsigned)pB[k].x, wB[k].x);
            EDGE((unsigned)pB[k].y, wB[k].y);
            EDGE((unsigned)pB[k].z, wB[k].z);
            EDGE((unsigned)pB[k].w, wB[k].w);
        }
    }
#undef EDGE
    __syncthreads();

    // node pass: unpack fields; ratio1 = 0.5*t1i/deni - 8 ; ratio2 = 4*t2i/deni
    double s1 = 0.0, s2 = 0.0;
    for (int n = tid; n < N_NODES; n += 512) {
        const unsigned long long pk = apk[n];
        const unsigned deni = (unsigned)((pk >> 26) & 0xFFFFFu);
        if (deni) {
            const unsigned t1i = (unsigned)(pk & 0x3FFFFFFu);
            const unsigned t2i = (unsigned)(pk >> 46);
            const double dinv = 1.0 / (double)deni;
            s1 += 0.5 * (double)t1i * dinv - 8.0;
            s2 += 4.0 * (double)t2i * dinv;
        }
    }
#pragma unroll
    for (int off = 32; off > 0; off >>= 1) {
        s1 += __shfl_down(s1, off, 64);
        s2 += __shfl_down(s2, off, 64);
    }
    const int wave = tid >> 6, lane = tid & 63;
    if (lane == 0) { wr1[wave] = s1; wr2[wave] = s2; }
    __syncthreads();
    if (tid == 0) {
        double a = 0.0, c = 0.0;
#pragma unroll
        for (int w = 0; w < 8; ++w) { a += wr1[w]; c += wr2[w]; }
#pragma unroll
        for (int k = 0; k < OUTF; ++k)
            feats[g * OUTF + k] = gat_b[k] +
                (float)((a * (double)W_node[k] + c * (double)W_edge[k]) / (double)N_NODES);
    }
}

// ---------------- head: 16 blocks (one per batch): LSTM + precomputed-M ----------------

__device__ __forceinline__ float fast_sigmoid(float v) { return 1.f / (1.f + __expf(-v)); }
__device__ __forceinline__ float fast_tanh(float v) {
    const float t = __expf(2.f * v);
    return (t - 1.f) / (t + 1.f);
}

__global__ __launch_bounds__(128) void lstm_head(
    const float* __restrict__ feats, const float* __restrict__ Mw,
    const float* __restrict__ b2w,
    const float* __restrict__ w_ih, const float* __restrict__ w_hh,
    const float* __restrict__ b_ih, const float* __restrict__ b_hh,
    float* __restrict__ out)
{
    __shared__ float s_M[FCC_OUTD * HID];
    __shared__ float s_b2[FCC_OUTD];
    __shared__ float s_xt[TT * OUTF];
    __shared__ float s_bias[96];
    __shared__ float s_xg[TT * 96];
    __shared__ float s_g[96];
    __shared__ float s_h[HID], s_c[HID];
    __shared__ float s_hs[TT * HID];

    const int b = blockIdx.x, tid = threadIdx.x;
    for (int i = tid; i < FCC_OUTD * HID; i += 128) s_M[i] = Mw[i];
    if (tid < FCC_OUTD) s_b2[tid] = b2w[tid];
    for (int i = tid; i < TT * OUTF; i += 128) s_xt[i] = feats[b * TT * OUTF + i];
    if (tid < 96) s_bias[tid] = b_ih[tid] + b_hh[tid];
    if (tid < HID) { s_h[tid] = 0.f; s_c[tid] = 0.f; }
    float rw_hh[HID];
    if (tid < 96) {
#pragma unroll
        for (int k = 0; k < HID; ++k) rw_hh[k] = w_hh[tid * HID + k];
    }
    __syncthreads();
    for (int u = tid; u < TT * 96; u += 128) {
        const int t = u / 96, j = u % 96;
        float acc = s_bias[j];
        const float* xt = &s_xt[t * OUTF];
#pragma unroll
        for (int k = 0; k < OUTF; ++k) acc += xt[k] * w_ih[j * OUTF + k];
        s_xg[u] = acc;
    }
    __syncthreads();
    for (int t = 0; t < TT; ++t) {
        if (tid < 96) {
            float acc = s_xg[t * 96 + tid];
#pragma unroll
            for (int k = 0; k < HID; ++k) acc += s_h[k] * rw_hh[k];
            s_g[tid] = acc;
        }
        __syncthreads();
        if (tid < HID) {
            const float i_ = fast_sigmoid(s_g[tid]);
            const float f_ = fast_sigmoid(s_g[24 + tid]);
            const float g_ = fast_tanh(s_g[48 + tid]);
            const float o_ = fast_sigmoid(s_g[72 + tid]);
            const float c = f_ * s_c[tid] + i_ * g_;
            s_c[tid] = c;
            const float hv = o_ * fast_tanh(c);
            s_h[tid] = hv;
            s_hs[t * HID + tid] = hv;
        }
        __syncthreads();
    }
    for (int u = tid; u < TT * FCC_OUTD; u += 128) {
        const int t = u / FCC_OUTD, j = u % FCC_OUTD;
        float acc = s_b2[j];
        const float* hr = &s_hs[t * HID];
#pragma unroll
        for (int h = 0; h < HID; ++h) acc += hr[h] * s_M[j * HID + h];
        out[(b * TT + t) * FCC_OUTD + j] = acc;
    }
}

extern "C" void kernel_launch(void* const* d_in, const int* in_sizes, int n_in,
                              void* d_out, int out_size, void* d_ws, size_t ws_size,
                              hipStream_t stream) {
    const float* x      = (const float*)d_in[0];
    const float* edge_w = (const float*)d_in[1];
    const int*   src    = (const int*)d_in[2];
    const int*   dst    = (const int*)d_in[3];
    const float* W_node = (const float*)d_in[4];
    const float* W_edge = (const float*)d_in[5];
    const float* attn_l = (const float*)d_in[6];
    const float* attn_e = (const float*)d_in[7];
    const float* attn_r = (const float*)d_in[8];
    const float* gat_b  = (const float*)d_in[9];
    const float* w_ih   = (const float*)d_in[10];
    const float* w_hh   = (const float*)d_in[11];
    const float* b_ih   = (const float*)d_in[12];
    const float* b_hh   = (const float*)d_in[13];
    const float* fc_w   = (const float*)d_in[14];
    const float* fc_b   = (const float*)d_in[15];
    const float* fcc_w  = (const float*)d_in[16];
    const float* fcc_b  = (const float*)d_in[17];

    char* ws = (char*)d_ws;
    unsigned* pack  = (unsigned*)(ws + WS_PACK);
    float*    feats = (float*)(ws + WS_FEATS);
    float*    Mw    = (float*)(ws + WS_M);
    float*    b2w   = (float*)(ws + WS_B2);
    float*    out   = (float*)d_out;

    build_pack<<<33, 1024, 0, stream>>>(src, dst, pack, fc_w, fc_b, fcc_w, fcc_b, Mw, b2w);
    gat_atomic<<<NG, 512, 0, stream>>>(x, edge_w, pack, W_node, W_edge,
                                       attn_l, attn_e, attn_r, gat_b, feats);
    lstm_head<<<BB, 128, 0, stream>>>(feats, Mw, b2w, w_ih, w_hh, b_ih, b_hh, out);
}

// Round 14
// 59.383 us; speedup vs baseline: 1.1071x; 1.1071x over previous
//
#include <hip/hip_runtime.h>
#include <math.h>

#define N_NODES 2000
#define N_EDGES 32000
#define BB 16
#define TT 20
#define NG (BB*TT)      // 320 graphs
#define OUTF 8
#define HID 24
#define FC_OUTD 160
#define FCC_OUTD 20
#define NPAIR 160
#define NWIN 3          // edge windows per pair -> 480 blocks

// u64 fixed-point pack per graph (one native ds_add_u64, R13-verified):
//   bits[ 0:26) t1' = sum num*(x+8) @ 2^12 ; bits[26:46) den @ 2^11 ; bits[46:64) t2 @ 2^9
// recover: ratio1 = 0.5*t1i/deni - 8 ; ratio2 = 4*t2i/deni

// ws layout (bytes)
#define WS_PACK   0         // u32[32000]
#define WS_FEATS  131072    // float[2560]
#define WS_M      141312    // float[480]
#define WS_B2     143232    // float[20]
#define WS_DUMP   147456    // u64[480][2][2000] = 15.36 MB

// ---------- builder: pack src|dst (+ extra block: fused fcc@fc projection) ----------

__global__ __launch_bounds__(1024) void build_pack(
    const int* __restrict__ src, const int* __restrict__ dst,
    unsigned* __restrict__ pack,
    const float* __restrict__ fc_w, const float* __restrict__ fc_b,
    const float* __restrict__ fcc_w, const float* __restrict__ fcc_b,
    float* __restrict__ Mout, float* __restrict__ b2out)
{
    const int tid = threadIdx.x;
    if (blockIdx.x == 32) {   // prep: M = fcc_w @ fc_w ; b2 = fcc_b + fcc_w @ fc_b
        if (tid < FCC_OUTD * HID) {
            const int j = tid / HID, h = tid % HID;
            float acc = 0.f;
#pragma unroll 4
            for (int m = 0; m < FC_OUTD; ++m)
                acc += fcc_w[j * FC_OUTD + m] * fc_w[m * HID + h];
            Mout[tid] = acc;
        } else if (tid < FCC_OUTD * HID + FCC_OUTD) {
            const int j = tid - FCC_OUTD * HID;
            float acc = fcc_b[j];
#pragma unroll 4
            for (int m = 0; m < FC_OUTD; ++m)
                acc += fcc_w[j * FC_OUTD + m] * fc_b[m];
            b2out[j] = acc;
        }
        return;
    }
    const int e = blockIdx.x * 1024 + tid;
    if (e < N_EDGES)
        pack[e] = (unsigned)src[e] | ((unsigned)dst[e] << 16);
}

// ---- GAT: 480 blocks = 160 graph-pairs x 3 edge-windows; 2 graphs share gathers ----

__global__ __launch_bounds__(512) void gat_pair(
    const float* __restrict__ x, const float* __restrict__ edge_w,
    const unsigned* __restrict__ pack,
    const float* __restrict__ W_node, const float* __restrict__ W_edge,
    const float* __restrict__ attn_l, const float* __restrict__ attn_e,
    const float* __restrict__ attn_r,
    unsigned long long* __restrict__ dump)
{
    __shared__ float2             xs2[N_NODES];     // 16 KB: {x_g0, x_g1}
    __shared__ unsigned long long apk[2][2008];     // 32.1 KB (pad 8 -> 16-bank stagger)

    const int b   = blockIdx.x;
    const int p   = b / NWIN;
    const int h   = b % NWIN;
    const int g0  = 2 * p, g1 = 2 * p + 1;
    const int tid = threadIdx.x;

    float cl = 0.f, ce = 0.f, cr = 0.f;
#pragma unroll
    for (int k = 0; k < OUTF; ++k) {
        cl += W_node[k] * attn_l[k];
        cr += W_node[k] * attn_r[k];
        ce += W_edge[k] * attn_e[k];
    }

    const float* x0 = x + (size_t)g0 * N_NODES;
    const float* x1 = x + (size_t)g1 * N_NODES;
    for (int n = tid; n < N_NODES; n += 512) {
        xs2[n] = make_float2(x0[n], x1[n]);
        apk[0][n] = 0ull; apk[1][n] = 0ull;
    }
    __syncthreads();

    // window bounds in int4-group units (8000 total)
    const int c0 = (h == 0) ? 0 : (h == 1) ? 2667 : 5334;
    const int c1 = (h == 0) ? 2667 : (h == 1) ? 5334 : 8000;

    const int4*   pk4 = (const int4*)pack;
    const float4* w04 = (const float4*)(edge_w + (size_t)g0 * N_EDGES);
    const float4* w14 = (const float4*)(edge_w + (size_t)g1 * N_EDGES);

#define PACK1(num, xv, wv)                                                \
    ( (unsigned long long)__float2uint_rn(fmaf((num) * 4096.0f, (xv),    \
                                               8.0f * (num) * 4096.0f))   \
    | ((unsigned long long)__float2uint_rn((num) * 2048.0f) << 26)        \
    | ((unsigned long long)__float2uint_rn((num) * (wv) * 512.0f) << 46) )

#pragma unroll 2
    for (int c = c0 + tid; c < c1; c += 512) {
        const int4   pv = pk4[c];
        const float4 wa = w04[c];
        const float4 wb = w14[c];
#pragma unroll
        for (int j = 0; j < 4; ++j) {
            const unsigned m = (unsigned)(&pv.x)[j];
            const int s = (int)(m & 0xffffu);
            const int d = (int)(m >> 16);
            const float2 xsv = xs2[s];      // ds_read_b64: both graphs
            const float2 xdv = xs2[d];      // ds_read_b64
            const float wA = (&wa.x)[j], wB = (&wb.x)[j];
            // graph 0
            float ev0 = cl * xsv.x + ce * wA + cr * xdv.x;
            ev0 = fmaxf(ev0, 0.2f * ev0);
            const float n0 = __expf(ev0);
            atomicAdd(&apk[0][d], PACK1(n0, xsv.x, wA));
            // graph 1
            float ev1 = cl * xsv.y + ce * wB + cr * xdv.y;
            ev1 = fmaxf(ev1, 0.2f * ev1);
            const float n1 = __expf(ev1);
            atomicAdd(&apk[1][d], PACK1(n1, xsv.y, wB));
        }
    }
#undef PACK1
    __syncthreads();

    for (int n = tid; n < N_NODES; n += 512) {
        dump[((size_t)b * 2 + 0) * N_NODES + n] = apk[0][n];
        dump[((size_t)b * 2 + 1) * N_NODES + n] = apk[1][n];
    }
}

// ---- combine: 320 blocks; sum 3 window partials, node pass, pooled reduce ----

__global__ __launch_bounds__(512) void combine_kernel(
    const unsigned long long* __restrict__ dump,
    const float* __restrict__ W_node, const float* __restrict__ W_edge,
    const float* __restrict__ gat_b, float* __restrict__ feats)
{
    __shared__ double wr1[8], wr2[8];
    const int g   = blockIdx.x;
    const int p   = g >> 1, gs = g & 1;
    const int tid = threadIdx.x;

    const unsigned long long* d0 = dump + ((size_t)(p * NWIN + 0) * 2 + gs) * N_NODES;
    const unsigned long long* d1 = dump + ((size_t)(p * NWIN + 1) * 2 + gs) * N_NODES;
    const unsigned long long* d2 = dump + ((size_t)(p * NWIN + 2) * 2 + gs) * N_NODES;

    double s1 = 0.0, s2 = 0.0;
    for (int n = tid; n < N_NODES; n += 512) {
        const unsigned long long pk = d0[n] + d1[n] + d2[n];   // field-wise safe (R13 bounds)
        const unsigned deni = (unsigned)((pk >> 26) & 0xFFFFFu);
        if (deni) {
            const unsigned t1i = (unsigned)(pk & 0x3FFFFFFu);
            const unsigned t2i = (unsigned)(pk >> 46);
            const double dinv = 1.0 / (double)deni;
            s1 += 0.5 * (double)t1i * dinv - 8.0;
            s2 += 4.0 * (double)t2i * dinv;
        }
    }
#pragma unroll
    for (int off = 32; off > 0; off >>= 1) {
        s1 += __shfl_down(s1, off, 64);
        s2 += __shfl_down(s2, off, 64);
    }
    const int wave = tid >> 6, lane = tid & 63;
    if (lane == 0) { wr1[wave] = s1; wr2[wave] = s2; }
    __syncthreads();
    if (tid == 0) {
        double a = 0.0, c = 0.0;
#pragma unroll
        for (int w = 0; w < 8; ++w) { a += wr1[w]; c += wr2[w]; }
#pragma unroll
        for (int k = 0; k < OUTF; ++k)
            feats[g * OUTF + k] = gat_b[k] +
                (float)((a * (double)W_node[k] + c * (double)W_edge[k]) / (double)N_NODES);
    }
}

// ---------------- head: 16 blocks (one per batch): LSTM + precomputed-M ----------------

__device__ __forceinline__ float fast_sigmoid(float v) { return 1.f / (1.f + __expf(-v)); }
__device__ __forceinline__ float fast_tanh(float v) {
    const float t = __expf(2.f * v);
    return (t - 1.f) / (t + 1.f);
}

__global__ __launch_bounds__(128) void lstm_head(
    const float* __restrict__ feats, const float* __restrict__ Mw,
    const float* __restrict__ b2w,
    const float* __restrict__ w_ih, const float* __restrict__ w_hh,
    const float* __restrict__ b_ih, const float* __restrict__ b_hh,
    float* __restrict__ out)
{
    __shared__ float s_M[FCC_OUTD * HID];
    __shared__ float s_b2[FCC_OUTD];
    __shared__ float s_xt[TT * OUTF];
    __shared__ float s_bias[96];
    __shared__ float s_xg[TT * 96];
    __shared__ float s_g[96];
    __shared__ float s_h[HID], s_c[HID];
    __shared__ float s_hs[TT * HID];

    const int b = blockIdx.x, tid = threadIdx.x;
    for (int i = tid; i < FCC_OUTD * HID; i += 128) s_M[i] = Mw[i];
    if (tid < FCC_OUTD) s_b2[tid] = b2w[tid];
    for (int i = tid; i < TT * OUTF; i += 128) s_xt[i] = feats[b * TT * OUTF + i];
    if (tid < 96) s_bias[tid] = b_ih[tid] + b_hh[tid];
    if (tid < HID) { s_h[tid] = 0.f; s_c[tid] = 0.f; }
    float rw_hh[HID];
    if (tid < 96) {
#pragma unroll
        for (int k = 0; k < HID; ++k) rw_hh[k] = w_hh[tid * HID + k];
    }
    __syncthreads();
    for (int u = tid; u < TT * 96; u += 128) {
        const int t = u / 96, j = u % 96;
        float acc = s_bias[j];
        const float* xt = &s_xt[t * OUTF];
#pragma unroll
        for (int k = 0; k < OUTF; ++k) acc += xt[k] * w_ih[j * OUTF + k];
        s_xg[u] = acc;
    }
    __syncthreads();
    for (int t = 0; t < TT; ++t) {
        if (tid < 96) {
            float acc = s_xg[t * 96 + tid];
#pragma unroll
            for (int k = 0; k < HID; ++k) acc += s_h[k] * rw_hh[k];
            s_g[tid] = acc;
        }
        __syncthreads();
        if (tid < HID) {
            const float i_ = fast_sigmoid(s_g[tid]);
            const float f_ = fast_sigmoid(s_g[24 + tid]);
            const float g_ = fast_tanh(s_g[48 + tid]);
            const float o_ = fast_sigmoid(s_g[72 + tid]);
            const float c = f_ * s_c[tid] + i_ * g_;
            s_c[tid] = c;
            const float hv = o_ * fast_tanh(c);
            s_h[tid] = hv;
            s_hs[t * HID + tid] = hv;
        }
        __syncthreads();
    }
    for (int u = tid; u < TT * FCC_OUTD; u += 128) {
        const int t = u / FCC_OUTD, j = u % FCC_OUTD;
        float acc = s_b2[j];
        const float* hr = &s_hs[t * HID];
#pragma unroll
        for (int h = 0; h < HID; ++h) acc += hr[h] * s_M[j * HID + h];
        out[(b * TT + t) * FCC_OUTD + j] = acc;
    }
}

extern "C" void kernel_launch(void* const* d_in, const int* in_sizes, int n_in,
                              void* d_out, int out_size, void* d_ws, size_t ws_size,
                              hipStream_t stream) {
    const float* x      = (const float*)d_in[0];
    const float* edge_w = (const float*)d_in[1];
    const int*   src    = (const int*)d_in[2];
    const int*   dst    = (const int*)d_in[3];
    const float* W_node = (const float*)d_in[4];
    const float* W_edge = (const float*)d_in[5];
    const float* attn_l = (const float*)d_in[6];
    const float* attn_e = (const float*)d_in[7];
    const float* attn_r = (const float*)d_in[8];
    const float* gat_b  = (const float*)d_in[9];
    const float* w_ih   = (const float*)d_in[10];
    const float* w_hh   = (const float*)d_in[11];
    const float* b_ih   = (const float*)d_in[12];
    const float* b_hh   = (const float*)d_in[13];
    const float* fc_w   = (const float*)d_in[14];
    const float* fc_b   = (const float*)d_in[15];
    const float* fcc_w  = (const float*)d_in[16];
    const float* fcc_b  = (const float*)d_in[17];

    char* ws = (char*)d_ws;
    unsigned*           pack  = (unsigned*)(ws + WS_PACK);
    float*              feats = (float*)(ws + WS_FEATS);
    float*              Mw    = (float*)(ws + WS_M);
    float*              b2w   = (float*)(ws + WS_B2);
    unsigned long long* dump  = (unsigned long long*)(ws + WS_DUMP);
    float*              out   = (float*)d_out;

    build_pack<<<33, 1024, 0, stream>>>(src, dst, pack, fc_w, fc_b, fcc_w, fcc_b, Mw, b2w);
    gat_pair<<<NPAIR * NWIN, 512, 0, stream>>>(x, edge_w, pack, W_node, W_edge,
                                               attn_l, attn_e, attn_r, dump);
    combine_kernel<<<NG, 512, 0, stream>>>(dump, W_node, W_edge, gat_b, feats);
    lstm_head<<<BB, 128, 0, stream>>>(feats, Mw, b2w, w_ih, w_hh, b_ih, b_hh, out);
}